// Round 5
// baseline (414.473 us; speedup 1.0000x reference)
//
#include <hip/hip_runtime.h>
#include <math.h>

#define N_NODES 50000
#define N_EDGES 800000
#define D 64

#define SCAN_BLOCK 256
#define SCAN_TILE  1024
#define N_TILES    ((N_NODES + SCAN_TILE - 1) / SCAN_TILE)   // 49

// ============================================================
// CSR build (once per call; dst is shared by all 3 layers)
// ============================================================
__global__ void hist_kernel(const int* __restrict__ dst, int* __restrict__ counts) {
    const int i = blockIdx.x * blockDim.x + threadIdx.x;
    if (i < N_EDGES) atomicAdd(&counts[dst[i]], 1);
}

__global__ void scan_partial(const int* __restrict__ counts, int* __restrict__ partials) {
    const int tile = blockIdx.x;
    const int base = tile * SCAN_TILE + threadIdx.x * 4;
    int4 c = make_int4(0, 0, 0, 0);
    if (base + 3 < N_NODES) c = *(const int4*)&counts[base];
    else {
        int* cp = (int*)&c;
        for (int j = 0; j < 4; ++j) if (base + j < N_NODES) cp[j] = counts[base + j];
    }
    int s = c.x + c.y + c.z + c.w;
    #pragma unroll
    for (int off = 32; off >= 1; off >>= 1) s += __shfl_xor(s, off, 64);
    __shared__ int red[SCAN_BLOCK / 64];
    if ((threadIdx.x & 63) == 0) red[threadIdx.x >> 6] = s;
    __syncthreads();
    if (threadIdx.x == 0) {
        int t = 0;
        #pragma unroll
        for (int i = 0; i < SCAN_BLOCK / 64; ++i) t += red[i];
        partials[tile] = t;
    }
}

__global__ void scan_offsets(int* __restrict__ partials, int* __restrict__ row_ptr_last) {
    const int lane = threadIdx.x;
    const int v = (lane < N_TILES) ? partials[lane] : 0;
    int inc = v;
    #pragma unroll
    for (int off = 1; off < 64; off <<= 1) {
        const int w = __shfl_up(inc, off, 64);
        if (lane >= off) inc += w;
    }
    if (lane < N_TILES) partials[lane] = inc - v;
    if (lane == 63) *row_ptr_last = inc;
}

__global__ void scan_write(const int* __restrict__ counts, const int* __restrict__ partials,
                           int* __restrict__ row_ptr, int* __restrict__ cursor) {
    const int tile = blockIdx.x;
    const int tid  = threadIdx.x;
    const int base = tile * SCAN_TILE + tid * 4;
    int4 c = make_int4(0, 0, 0, 0);
    if (base + 3 < N_NODES) c = *(const int4*)&counts[base];
    else {
        int* cp = (int*)&c;
        for (int j = 0; j < 4; ++j) if (base + j < N_NODES) cp[j] = counts[base + j];
    }
    const int s = c.x + c.y + c.z + c.w;
    __shared__ int sh[SCAN_BLOCK];
    sh[tid] = s;
    __syncthreads();
    for (int off = 1; off < SCAN_BLOCK; off <<= 1) {
        const int w = (tid >= off) ? sh[tid - off] : 0;
        __syncthreads();
        sh[tid] += w;
        __syncthreads();
    }
    int run = partials[tile] + sh[tid] - s;
    const int* cp = (const int*)&c;
    int rp[4];
    #pragma unroll
    for (int j = 0; j < 4; ++j) { rp[j] = run; run += cp[j]; }
    if (base + 3 < N_NODES) {
        *(int4*)&row_ptr[base] = make_int4(rp[0], rp[1], rp[2], rp[3]);
        *(int4*)&cursor[base]  = make_int4(rp[0], rp[1], rp[2], rp[3]);
    } else {
        for (int j = 0; j < 4; ++j)
            if (base + j < N_NODES) { row_ptr[base + j] = rp[j]; cursor[base + j] = rp[j]; }
    }
}

__global__ void scatter_kernel(const int* __restrict__ src, const int* __restrict__ dst,
                               int* __restrict__ cursor, int* __restrict__ csr_src) {
    const int i = blockIdx.x * blockDim.x + threadIdx.x;
    if (i >= N_EDGES) return;
    const int pos = atomicAdd(&cursor[dst[i]], 1);
    csr_src[pos] = src[i];
}

// ============================================================
// K1: z = h @ W.T + b — lane = row, h row register-resident,
//     4 waves/block each computing 16 output columns (TLP fix).
//     W/b/a read at wave-uniform addresses -> scalar loads.
// ============================================================
__global__ __launch_bounds__(256) void node_linear_reg(
    const float* __restrict__ h, float* __restrict__ z,
    const float* __restrict__ W, const float* __restrict__ b,
    const float* __restrict__ a, const float* __restrict__ ab,
    float* __restrict__ s_src, float* __restrict__ s_dst)
{
    const int lane = threadIdx.x & 63;
    const int wv   = threadIdx.x >> 6;          // 0..3: column group
    const int row  = blockIdx.x * 64 + lane;
    const bool ok  = row < N_NODES;
    const int rsafe = ok ? row : (N_NODES - 1);

    // whole h row in registers: 16 x float4
    float4 hv[16];
    const float4* hp = (const float4*)(h + (size_t)rsafe * D);
    #pragma unroll
    for (int i = 0; i < 16; ++i) hv[i] = hp[i];

    float t0 = 0.f, t1 = 0.f;
    float4* zp = (float4*)(z + (size_t)rsafe * D);

    #pragma unroll
    for (int j4 = 0; j4 < 4; ++j4) {             // 4 col-quads for this wave
        const int j = wv * 16 + j4 * 4;          // wave-uniform
        float acc0 = b[j + 0], acc1 = b[j + 1], acc2 = b[j + 2], acc3 = b[j + 3];
        const float* w0 = &W[(j + 0) * D];
        const float* w1 = &W[(j + 1) * D];
        const float* w2 = &W[(j + 2) * D];
        const float* w3 = &W[(j + 3) * D];
        #pragma unroll
        for (int k4 = 0; k4 < 16; ++k4) {
            const float4 hq = hv[k4];
            const int k = k4 * 4;
            acc0 = fmaf(hq.x, w0[k + 0], acc0); acc0 = fmaf(hq.y, w0[k + 1], acc0);
            acc0 = fmaf(hq.z, w0[k + 2], acc0); acc0 = fmaf(hq.w, w0[k + 3], acc0);
            acc1 = fmaf(hq.x, w1[k + 0], acc1); acc1 = fmaf(hq.y, w1[k + 1], acc1);
            acc1 = fmaf(hq.z, w1[k + 2], acc1); acc1 = fmaf(hq.w, w1[k + 3], acc1);
            acc2 = fmaf(hq.x, w2[k + 0], acc2); acc2 = fmaf(hq.y, w2[k + 1], acc2);
            acc2 = fmaf(hq.z, w2[k + 2], acc2); acc2 = fmaf(hq.w, w2[k + 3], acc2);
            acc3 = fmaf(hq.x, w3[k + 0], acc3); acc3 = fmaf(hq.y, w3[k + 1], acc3);
            acc3 = fmaf(hq.z, w3[k + 2], acc3); acc3 = fmaf(hq.w, w3[k + 3], acc3);
        }
        t0 = fmaf(acc0, a[j + 0], t0); t1 = fmaf(acc0, a[64 + j + 0], t1);
        t0 = fmaf(acc1, a[j + 1], t0); t1 = fmaf(acc1, a[64 + j + 1], t1);
        t0 = fmaf(acc2, a[j + 2], t0); t1 = fmaf(acc2, a[64 + j + 2], t1);
        t0 = fmaf(acc3, a[j + 3], t0); t1 = fmaf(acc3, a[64 + j + 3], t1);
        if (ok) zp[wv * 4 + j4] = make_float4(acc0, acc1, acc2, acc3);
    }

    // reduce t0,t1 partials across the 4 column-group waves
    __shared__ float sh0[4][64], sh1[4][64];
    sh0[wv][lane] = t0;
    sh1[wv][lane] = t1;
    __syncthreads();
    if (wv == 0 && ok) {
        const float T0 = sh0[0][lane] + sh0[1][lane] + sh0[2][lane] + sh0[3][lane];
        const float T1 = sh1[0][lane] + sh1[1][lane] + sh1[2][lane] + sh1[3][lane];
        s_src[row] = T0;
        s_dst[row] = T1 + ab[0];
    }
}

// ============================================================
// K2: fused per-dst-node softmax + aggregate + normalize (+ReLU)
// ============================================================
template<bool RELU>
__global__ void gat_aggregate(const int* __restrict__ row_ptr, const int* __restrict__ csr_src,
                              const float* __restrict__ s_src, const float* __restrict__ s_dst,
                              const float* __restrict__ z, float* __restrict__ out) {
    const int lane = threadIdx.x & 63;
    const int node = blockIdx.x * (blockDim.x >> 6) + (threadIdx.x >> 6);
    if (node >= N_NODES) return;
    const int beg = row_ptr[node];
    const int end = row_ptr[node + 1];
    if (beg == end) { out[node * D + lane] = 0.f; return; }
    const float sd = s_dst[node];
    float m = -INFINITY;
    float den = 0.f;
    float acc = 0.f;
    for (int base = beg; base < end; base += 64) {
        const int n = min(64, end - base);
        const int sidx = (lane < n) ? csr_src[base + lane] : 0;
        float e = -INFINITY;
        if (lane < n) {
            e = s_src[sidx] + sd;
            e = e > 0.f ? e : 0.01f * e;
        }
        float mc = e;
        #pragma unroll
        for (int off = 32; off >= 1; off >>= 1) mc = fmaxf(mc, __shfl_xor(mc, off, 64));
        if (mc > m) {
            const float scale = __expf(m - mc);
            den *= scale; acc *= scale; m = mc;
        }
        const float ex = __expf(e - m);
        den += ex;
        for (int t = 0; t < n; ++t) {
            const float ext = __shfl(ex, t, 64);
            const int   st  = __shfl(sidx, t, 64);
            acc = fmaf(ext, z[st * D + lane], acc);
        }
    }
    #pragma unroll
    for (int off = 32; off >= 1; off >>= 1) den += __shfl_xor(den, off, 64);
    float v = acc / den;
    if (RELU) v = fmaxf(v, 0.f);
    out[node * D + lane] = v;
}

// ============================================================
extern "C" void kernel_launch(void* const* d_in, const int* in_sizes, int n_in,
                              void* d_out, int out_size, void* d_ws, size_t ws_size,
                              hipStream_t stream) {
    const float* x   = (const float*)d_in[0];
    const int*   src = (const int*)d_in[1];
    const int*   dst = (const int*)d_in[2];
    float* out = (float*)d_out;

    // workspace carve-out (~17 MB)
    char* w = (char*)d_ws;
    float* zbuf     = (float*)w; w += (size_t)N_NODES * D * sizeof(float);
    float* s_src    = (float*)w; w += (size_t)N_NODES * sizeof(float);
    float* s_dst    = (float*)w; w += (size_t)N_NODES * sizeof(float);
    int*   counts   = (int*)w;   w += (size_t)N_NODES * sizeof(int);
    int*   row_ptr  = (int*)w;   w += (size_t)(N_NODES + 1) * sizeof(int);
    int*   cursor   = (int*)w;   w += (size_t)N_NODES * sizeof(int);
    int*   csr_src  = (int*)w;   w += (size_t)N_EDGES * sizeof(int);
    int*   partials = (int*)w;   w += (size_t)N_TILES * sizeof(int);

    // ---- CSR build (dst shared by all layers) ----
    hipMemsetAsync(counts, 0, (size_t)N_NODES * sizeof(int), stream);
    hist_kernel<<<(N_EDGES + 255) / 256, 256, 0, stream>>>(dst, counts);
    scan_partial<<<N_TILES, SCAN_BLOCK, 0, stream>>>(counts, partials);
    scan_offsets<<<1, 64, 0, stream>>>(partials, &row_ptr[N_NODES]);
    scan_write<<<N_TILES, SCAN_BLOCK, 0, stream>>>(counts, partials, row_ptr, cursor);
    scatter_kernel<<<(N_EDGES + 255) / 256, 256, 0, stream>>>(src, dst, cursor, csr_src);

    const int grid_k1  = (N_NODES + 63) / 64;   // 782 blocks x 4 waves (col-split)
    const int grid_agg = (N_NODES + 3) / 4;     // 12500

    for (int layer = 0; layer < 3; ++layer) {
        const float* W  = (const float*)d_in[3 + 4 * layer];
        const float* b  = (const float*)d_in[4 + 4 * layer];
        const float* a  = (const float*)d_in[5 + 4 * layer];
        const float* ab = (const float*)d_in[6 + 4 * layer];
        const float* hin = (layer == 0) ? x : out;   // d_out doubles as h buffer

        node_linear_reg<<<grid_k1, 256, 0, stream>>>(hin, zbuf, W, b, a, ab, s_src, s_dst);
        if (layer < 2) {
            gat_aggregate<true ><<<grid_agg, 256, 0, stream>>>(row_ptr, csr_src, s_src, s_dst, zbuf, out);
        } else {
            gat_aggregate<false><<<grid_agg, 256, 0, stream>>>(row_ptr, csr_src, s_src, s_dst, zbuf, out);
        }
    }
}

// Round 6
// 285.873 us; speedup vs baseline: 1.4498x; 1.4498x over previous
//
#include <hip/hip_runtime.h>
#include <math.h>

#define N_NODES 50000
#define N_EDGES 800000
#define D 64

#define SCAN_BLOCK 256
#define SCAN_TILE  1024
#define N_TILES    ((N_NODES + SCAN_TILE - 1) / SCAN_TILE)   // 49

// ============================================================
// CSR build (once per call; dst is shared by all 3 layers)
// ============================================================
__global__ void hist_kernel(const int* __restrict__ dst, int* __restrict__ counts) {
    const int i = blockIdx.x * blockDim.x + threadIdx.x;
    if (i < N_EDGES) atomicAdd(&counts[dst[i]], 1);
}

__global__ void scan_partial(const int* __restrict__ counts, int* __restrict__ partials) {
    const int tile = blockIdx.x;
    const int base = tile * SCAN_TILE + threadIdx.x * 4;
    int4 c = make_int4(0, 0, 0, 0);
    if (base + 3 < N_NODES) c = *(const int4*)&counts[base];
    else {
        int* cp = (int*)&c;
        for (int j = 0; j < 4; ++j) if (base + j < N_NODES) cp[j] = counts[base + j];
    }
    int s = c.x + c.y + c.z + c.w;
    #pragma unroll
    for (int off = 32; off >= 1; off >>= 1) s += __shfl_xor(s, off, 64);
    __shared__ int red[SCAN_BLOCK / 64];
    if ((threadIdx.x & 63) == 0) red[threadIdx.x >> 6] = s;
    __syncthreads();
    if (threadIdx.x == 0) {
        int t = 0;
        #pragma unroll
        for (int i = 0; i < SCAN_BLOCK / 64; ++i) t += red[i];
        partials[tile] = t;
    }
}

__global__ void scan_offsets(int* __restrict__ partials, int* __restrict__ row_ptr_last) {
    const int lane = threadIdx.x;
    const int v = (lane < N_TILES) ? partials[lane] : 0;
    int inc = v;
    #pragma unroll
    for (int off = 1; off < 64; off <<= 1) {
        const int w = __shfl_up(inc, off, 64);
        if (lane >= off) inc += w;
    }
    if (lane < N_TILES) partials[lane] = inc - v;
    if (lane == 63) *row_ptr_last = inc;
}

__global__ void scan_write(const int* __restrict__ counts, const int* __restrict__ partials,
                           int* __restrict__ row_ptr, int* __restrict__ cursor) {
    const int tile = blockIdx.x;
    const int tid  = threadIdx.x;
    const int base = tile * SCAN_TILE + tid * 4;
    int4 c = make_int4(0, 0, 0, 0);
    if (base + 3 < N_NODES) c = *(const int4*)&counts[base];
    else {
        int* cp = (int*)&c;
        for (int j = 0; j < 4; ++j) if (base + j < N_NODES) cp[j] = counts[base + j];
    }
    const int s = c.x + c.y + c.z + c.w;
    __shared__ int sh[SCAN_BLOCK];
    sh[tid] = s;
    __syncthreads();
    for (int off = 1; off < SCAN_BLOCK; off <<= 1) {
        const int w = (tid >= off) ? sh[tid - off] : 0;
        __syncthreads();
        sh[tid] += w;
        __syncthreads();
    }
    int run = partials[tile] + sh[tid] - s;
    const int* cp = (const int*)&c;
    int rp[4];
    #pragma unroll
    for (int j = 0; j < 4; ++j) { rp[j] = run; run += cp[j]; }
    if (base + 3 < N_NODES) {
        *(int4*)&row_ptr[base] = make_int4(rp[0], rp[1], rp[2], rp[3]);
        *(int4*)&cursor[base]  = make_int4(rp[0], rp[1], rp[2], rp[3]);
    } else {
        for (int j = 0; j < 4; ++j)
            if (base + j < N_NODES) { row_ptr[base + j] = rp[j]; cursor[base + j] = rp[j]; }
    }
}

__global__ void scatter_kernel(const int* __restrict__ src, const int* __restrict__ dst,
                               int* __restrict__ cursor, int* __restrict__ csr_src) {
    const int i = blockIdx.x * blockDim.x + threadIdx.x;
    if (i >= N_EDGES) return;
    const int pos = atomicAdd(&cursor[dst[i]], 1);
    csr_src[pos] = src[i];
}

// ============================================================
// K1: z = h @ W.T + b — wave owns 8 rows, lane = output column.
//     W transposed in LDS (pad 65, conflict-free); h rows read at
//     wave-uniform addresses (s_load, SMEM pipe); coalesced z stores.
// ============================================================
#define NL_ROWS 8                 // rows per wave; 50000 % 8 == 0
__global__ __launch_bounds__(256) void node_linear_gemm(
    const float* __restrict__ h, float* __restrict__ z,
    const float* __restrict__ W, const float* __restrict__ b,
    const float* __restrict__ a, const float* __restrict__ ab,
    float* __restrict__ s_src, float* __restrict__ s_dst)
{
    __shared__ float Wt[64 * 65];           // Wt[k*65 + j] = W[j*64 + k]
    for (int idx = threadIdx.x; idx < D * D; idx += 256) {
        const int j = idx >> 6, k = idx & 63;
        Wt[k * 65 + j] = W[idx];
    }
    __syncthreads();

    const int lane = threadIdx.x & 63;
    const int wv   = __builtin_amdgcn_readfirstlane(threadIdx.x >> 6);
    const int row0 = (blockIdx.x * 4 + wv) * NL_ROWS;
    if (row0 >= N_NODES) return;            // whole wave OOB (after barrier)

    const float bj  = b[lane];
    const float alo = a[lane];
    const float ahi = a[64 + lane];

    // wave-uniform row base pointers -> scalar loads of h
    const float* hr[NL_ROWS];
    #pragma unroll
    for (int r = 0; r < NL_ROWS; ++r) hr[r] = h + (size_t)(row0 + r) * D;

    float acc[NL_ROWS];
    #pragma unroll
    for (int r = 0; r < NL_ROWS; ++r) acc[r] = bj;

    #pragma unroll 4
    for (int k = 0; k < D; ++k) {
        const float wkj = Wt[k * 65 + lane];
        #pragma unroll
        for (int r = 0; r < NL_ROWS; ++r)
            acc[r] = fmaf(hr[r][k], wkj, acc[r]);
    }

    #pragma unroll
    for (int r = 0; r < NL_ROWS; ++r) {
        z[(size_t)(row0 + r) * D + lane] = acc[r];
        float u = acc[r] * alo;
        float v = acc[r] * ahi;
        #pragma unroll
        for (int off = 32; off >= 1; off >>= 1) {
            u += __shfl_xor(u, off, 64);
            v += __shfl_xor(v, off, 64);
        }
        if (lane == 0) { s_src[row0 + r] = u; s_dst[row0 + r] = v + ab[0]; }
    }
}

// ============================================================
// K2: fused per-dst softmax + aggregate + normalize (+ReLU).
//     Chunk (ex,sidx) staged in LDS; inner loop 4 edges deep with
//     independent accumulators (MLP) and uniform-address broadcasts.
// ============================================================
template<bool RELU>
__global__ __launch_bounds__(256) void gat_aggregate(
    const int* __restrict__ row_ptr, const int* __restrict__ csr_src,
    const float* __restrict__ s_src, const float* __restrict__ s_dst,
    const float* __restrict__ z, float* __restrict__ out)
{
    __shared__ float sh_ex[4][64];
    __shared__ int   sh_si[4][64];
    const int lane = threadIdx.x & 63;
    const int wv   = threadIdx.x >> 6;
    const int node = blockIdx.x * 4 + wv;
    if (node >= N_NODES) return;
    const int beg = row_ptr[node];
    const int end = row_ptr[node + 1];
    if (beg == end) { out[(size_t)node * D + lane] = 0.f; return; }
    const float sd = s_dst[node];

    float m = -INFINITY;
    float den = 0.f;                 // per-lane partial, reduced at the end
    float a0 = 0.f, a1 = 0.f, a2 = 0.f, a3 = 0.f;

    for (int base = beg; base < end; base += 64) {
        const int n = min(64, end - base);
        const int sidx = (lane < n) ? csr_src[base + lane] : 0;
        float e = -INFINITY;
        if (lane < n) {
            e = s_src[sidx] + sd;
            e = e > 0.f ? e : 0.01f * e;          // leaky_relu
        }
        float mc = e;
        #pragma unroll
        for (int off = 32; off >= 1; off >>= 1) mc = fmaxf(mc, __shfl_xor(mc, off, 64));
        if (mc > m) {                              // online rescale
            const float scale = __expf(m - mc);
            den *= scale; a0 *= scale; a1 *= scale; a2 *= scale; a3 *= scale;
            m = mc;
        }
        const float ex = __expf(e - m);            // 0 for pad lanes
        den += ex;
        sh_ex[wv][lane] = ex;
        sh_si[wv][lane] = sidx;                    // pad lanes: sidx=0, weight 0
        const int nn = (n + 3) & ~3;
        for (int t = 0; t < nn; t += 4) {
            const float4 wq = *(const float4*)&sh_ex[wv][t];  // uniform broadcast
            const int4   sq = *(const int4*)  &sh_si[wv][t];
            const float z0 = z[(size_t)sq.x * D + lane];
            const float z1 = z[(size_t)sq.y * D + lane];
            const float z2 = z[(size_t)sq.z * D + lane];
            const float z3 = z[(size_t)sq.w * D + lane];
            a0 = fmaf(wq.x, z0, a0);
            a1 = fmaf(wq.y, z1, a1);
            a2 = fmaf(wq.z, z2, a2);
            a3 = fmaf(wq.w, z3, a3);
        }
    }
    #pragma unroll
    for (int off = 32; off >= 1; off >>= 1) den += __shfl_xor(den, off, 64);
    float v = ((a0 + a1) + (a2 + a3)) / den;
    if (RELU) v = fmaxf(v, 0.f);
    out[(size_t)node * D + lane] = v;
}

// ============================================================
extern "C" void kernel_launch(void* const* d_in, const int* in_sizes, int n_in,
                              void* d_out, int out_size, void* d_ws, size_t ws_size,
                              hipStream_t stream) {
    const float* x   = (const float*)d_in[0];
    const int*   src = (const int*)d_in[1];
    const int*   dst = (const int*)d_in[2];
    float* out = (float*)d_out;

    // workspace carve-out (~17 MB)
    char* w = (char*)d_ws;
    float* zbuf     = (float*)w; w += (size_t)N_NODES * D * sizeof(float);
    float* s_src    = (float*)w; w += (size_t)N_NODES * sizeof(float);
    float* s_dst    = (float*)w; w += (size_t)N_NODES * sizeof(float);
    int*   counts   = (int*)w;   w += (size_t)N_NODES * sizeof(int);
    int*   row_ptr  = (int*)w;   w += (size_t)(N_NODES + 1) * sizeof(int);
    int*   cursor   = (int*)w;   w += (size_t)N_NODES * sizeof(int);
    int*   csr_src  = (int*)w;   w += (size_t)N_EDGES * sizeof(int);
    int*   partials = (int*)w;   w += (size_t)N_TILES * sizeof(int);

    // ---- CSR build (dst shared by all layers) ----
    hipMemsetAsync(counts, 0, (size_t)N_NODES * sizeof(int), stream);
    hist_kernel<<<(N_EDGES + 255) / 256, 256, 0, stream>>>(dst, counts);
    scan_partial<<<N_TILES, SCAN_BLOCK, 0, stream>>>(counts, partials);
    scan_offsets<<<1, 64, 0, stream>>>(partials, &row_ptr[N_NODES]);
    scan_write<<<N_TILES, SCAN_BLOCK, 0, stream>>>(counts, partials, row_ptr, cursor);
    scatter_kernel<<<(N_EDGES + 255) / 256, 256, 0, stream>>>(src, dst, cursor, csr_src);

    const int grid_k1  = (N_NODES + 4 * NL_ROWS - 1) / (4 * NL_ROWS);  // 1563
    const int grid_agg = (N_NODES + 3) / 4;                            // 12500

    for (int layer = 0; layer < 3; ++layer) {
        const float* W  = (const float*)d_in[3 + 4 * layer];
        const float* b  = (const float*)d_in[4 + 4 * layer];
        const float* a  = (const float*)d_in[5 + 4 * layer];
        const float* ab = (const float*)d_in[6 + 4 * layer];
        const float* hin = (layer == 0) ? x : out;   // d_out doubles as h buffer

        node_linear_gemm<<<grid_k1, 256, 0, stream>>>(hin, zbuf, W, b, a, ab, s_src, s_dst);
        if (layer < 2) {
            gat_aggregate<true ><<<grid_agg, 256, 0, stream>>>(row_ptr, csr_src, s_src, s_dst, zbuf, out);
        } else {
            gat_aggregate<false><<<grid_agg, 256, 0, stream>>>(row_ptr, csr_src, s_src, s_dst, zbuf, out);
        }
    }
}

// Round 7
// 215.541 us; speedup vs baseline: 1.9229x; 1.3263x over previous
//
#include <hip/hip_runtime.h>
#include <math.h>

#define N_NODES 50000
#define N_EDGES 800000
#define D 64

#define NB 256                    // dst buckets
#define NBLK 256                  // blocks in bucket hist/scatter
#define BUCKET_NODES 196          // ceil(50000/256); 256*196 = 50176
#define TILE 3125                 // 800000 / 256 exactly

// ============================================================
// Generic 3-phase exclusive scan (1024 elems/block)
// ============================================================
template<int N>
__global__ void scan_partial_g(const int* __restrict__ in, int* __restrict__ partials) {
    const int base = blockIdx.x * 1024 + threadIdx.x * 4;
    int4 c = make_int4(0, 0, 0, 0);
    if (base + 3 < N) c = *(const int4*)&in[base];
    else { int* cp = (int*)&c; for (int j = 0; j < 4; ++j) if (base + j < N) cp[j] = in[base + j]; }
    int s = c.x + c.y + c.z + c.w;
    #pragma unroll
    for (int off = 32; off >= 1; off >>= 1) s += __shfl_xor(s, off, 64);
    __shared__ int red[4];
    if ((threadIdx.x & 63) == 0) red[threadIdx.x >> 6] = s;
    __syncthreads();
    if (threadIdx.x == 0) partials[blockIdx.x] = red[0] + red[1] + red[2] + red[3];
}

__global__ void scan_offsets_g(int* __restrict__ partials, int nt, int* __restrict__ total_out) {
    const int lane = threadIdx.x;
    const int v = (lane < nt) ? partials[lane] : 0;
    int inc = v;
    #pragma unroll
    for (int off = 1; off < 64; off <<= 1) {
        const int w = __shfl_up(inc, off, 64);
        if (lane >= off) inc += w;
    }
    if (lane < nt) partials[lane] = inc - v;
    if (total_out != nullptr && lane == 63) *total_out = inc;
}

template<int N>
__global__ void scan_write_g(const int* __restrict__ in, const int* __restrict__ partials,
                             int* __restrict__ out) {
    const int tid  = threadIdx.x;
    const int base = blockIdx.x * 1024 + tid * 4;
    int4 c = make_int4(0, 0, 0, 0);
    if (base + 3 < N) c = *(const int4*)&in[base];
    else { int* cp = (int*)&c; for (int j = 0; j < 4; ++j) if (base + j < N) cp[j] = in[base + j]; }
    const int s = c.x + c.y + c.z + c.w;
    __shared__ int sh[256];
    sh[tid] = s;
    __syncthreads();
    for (int off = 1; off < 256; off <<= 1) {
        const int w = (tid >= off) ? sh[tid - off] : 0;
        __syncthreads();
        sh[tid] += w;
        __syncthreads();
    }
    int run = partials[blockIdx.x] + sh[tid] - s;
    const int* cp = (const int*)&c;
    int rp[4];
    #pragma unroll
    for (int j = 0; j < 4; ++j) { rp[j] = run; run += cp[j]; }
    if (base + 3 < N) *(int4*)&out[base] = make_int4(rp[0], rp[1], rp[2], rp[3]);
    else for (int j = 0; j < 4; ++j) if (base + j < N) out[base + j] = rp[j];
}

// ============================================================
// Bucketed CSR build — no global atomics, XCD-local final writes
// ============================================================
__global__ __launch_bounds__(256) void bucket_hist(const int* __restrict__ dst,
                                                   int* __restrict__ Acnt) {
    __shared__ int hist[NB];
    for (int i = threadIdx.x; i < NB; i += 256) hist[i] = 0;
    __syncthreads();
    const int base = blockIdx.x * TILE;
    for (int i = threadIdx.x; i < TILE; i += 256)
        atomicAdd(&hist[dst[base + i] / BUCKET_NODES], 1);
    __syncthreads();
    for (int bk = threadIdx.x; bk < NB; bk += 256)
        Acnt[bk * NBLK + blockIdx.x] = hist[bk];
}

__global__ __launch_bounds__(256) void bucket_scatter(const int* __restrict__ src,
                                                      const int* __restrict__ dst,
                                                      const int* __restrict__ offs,
                                                      int2* __restrict__ staging) {
    __shared__ int cur[NB];
    for (int i = threadIdx.x; i < NB; i += 256) cur[i] = offs[i * NBLK + blockIdx.x];
    __syncthreads();
    const int base = blockIdx.x * TILE;
    for (int i = threadIdx.x; i < TILE; i += 256) {
        const int s = src[base + i], d = dst[base + i];
        const int pos = atomicAdd(&cur[d / BUCKET_NODES], 1);
        staging[pos] = make_int2(s, d);
    }
}

__global__ __launch_bounds__(256) void node_counts(const int2* __restrict__ staging,
                                                   const int* __restrict__ offs,
                                                   int* __restrict__ counts) {
    __shared__ int cnt[BUCKET_NODES];
    const int b = blockIdx.x;
    for (int i = threadIdx.x; i < BUCKET_NODES; i += 256) cnt[i] = 0;
    __syncthreads();
    const int s0 = offs[b * NBLK];
    const int s1 = (b == NB - 1) ? N_EDGES : offs[(b + 1) * NBLK];
    for (int i = s0 + threadIdx.x; i < s1; i += 256)
        atomicAdd(&cnt[staging[i].y - b * BUCKET_NODES], 1);
    __syncthreads();
    for (int i = threadIdx.x; i < BUCKET_NODES; i += 256) {
        const int node = b * BUCKET_NODES + i;
        if (node < N_NODES) counts[node] = cnt[i];
    }
}

__global__ __launch_bounds__(256) void bucket_to_csr(const int2* __restrict__ staging,
                                                     const int* __restrict__ offs,
                                                     const int* __restrict__ row_ptr,
                                                     int* __restrict__ csr_src) {
    __shared__ int cur[BUCKET_NODES];
    const int b = blockIdx.x;
    for (int i = threadIdx.x; i < BUCKET_NODES; i += 256) {
        const int node = b * BUCKET_NODES + i;
        cur[i] = (node < N_NODES) ? row_ptr[node] : 0;
    }
    __syncthreads();
    const int s0 = offs[b * NBLK];
    const int s1 = (b == NB - 1) ? N_EDGES : offs[(b + 1) * NBLK];
    for (int i = s0 + threadIdx.x; i < s1; i += 256) {
        const int2 e = staging[i];
        const int pos = atomicAdd(&cur[e.y - b * BUCKET_NODES], 1);
        csr_src[pos] = e.x;
    }
}

// ---- fallback CSR build (used only if ws too small) ----
__global__ void hist_kernel(const int* __restrict__ dst, int* __restrict__ counts) {
    const int i = blockIdx.x * blockDim.x + threadIdx.x;
    if (i < N_EDGES) atomicAdd(&counts[dst[i]], 1);
}
__global__ void copy_kernel(const int* __restrict__ in, int* __restrict__ out, int n) {
    const int i = blockIdx.x * blockDim.x + threadIdx.x;
    if (i < n) out[i] = in[i];
}
__global__ void scatter_kernel(const int* __restrict__ src, const int* __restrict__ dst,
                               int* __restrict__ cursor, int* __restrict__ csr_src) {
    const int i = blockIdx.x * blockDim.x + threadIdx.x;
    if (i >= N_EDGES) return;
    const int pos = atomicAdd(&cursor[dst[i]], 1);
    csr_src[pos] = src[i];
}

// ============================================================
// K1: z = h @ W.T + b — wave owns 8 rows, lane = output column.
// ============================================================
#define NL_ROWS 8
__global__ __launch_bounds__(256) void node_linear_gemm(
    const float* __restrict__ h, float* __restrict__ z,
    const float* __restrict__ W, const float* __restrict__ b,
    const float* __restrict__ a, const float* __restrict__ ab,
    float* __restrict__ s_src, float* __restrict__ s_dst)
{
    __shared__ float Wt[64 * 65];           // Wt[k*65 + j] = W[j*64 + k]
    for (int idx = threadIdx.x; idx < D * D; idx += 256) {
        const int j = idx >> 6, k = idx & 63;
        Wt[k * 65 + j] = W[idx];
    }
    __syncthreads();

    const int lane = threadIdx.x & 63;
    const int wv   = __builtin_amdgcn_readfirstlane(threadIdx.x >> 6);
    const int row0 = (blockIdx.x * 4 + wv) * NL_ROWS;
    if (row0 >= N_NODES) return;

    const float bj  = b[lane];
    const float alo = a[lane];
    const float ahi = a[64 + lane];

    const float* hr[NL_ROWS];
    #pragma unroll
    for (int r = 0; r < NL_ROWS; ++r) hr[r] = h + (size_t)(row0 + r) * D;

    float acc[NL_ROWS];
    #pragma unroll
    for (int r = 0; r < NL_ROWS; ++r) acc[r] = bj;

    #pragma unroll 4
    for (int k = 0; k < D; ++k) {
        const float wkj = Wt[k * 65 + lane];
        #pragma unroll
        for (int r = 0; r < NL_ROWS; ++r)
            acc[r] = fmaf(hr[r][k], wkj, acc[r]);
    }

    #pragma unroll
    for (int r = 0; r < NL_ROWS; ++r) {
        z[(size_t)(row0 + r) * D + lane] = acc[r];
        float u = acc[r] * alo;
        float v = acc[r] * ahi;
        #pragma unroll
        for (int off = 32; off >= 1; off >>= 1) {
            u += __shfl_xor(u, off, 64);
            v += __shfl_xor(v, off, 64);
        }
        if (lane == 0) { s_src[row0 + r] = u; s_dst[row0 + r] = v + ab[0]; }
    }
}

// ============================================================
// K2: fused per-dst softmax + aggregate + normalize (+ReLU).
//     8 independent edge-gathers in flight per iteration.
// ============================================================
template<bool RELU>
__global__ __launch_bounds__(256) void gat_aggregate(
    const int* __restrict__ row_ptr, const int* __restrict__ csr_src,
    const float* __restrict__ s_src, const float* __restrict__ s_dst,
    const float* __restrict__ z, float* __restrict__ out)
{
    __shared__ float sh_ex[4][64];
    __shared__ int   sh_si[4][64];
    const int lane = threadIdx.x & 63;
    const int wv   = threadIdx.x >> 6;
    const int node = blockIdx.x * 4 + wv;
    if (node >= N_NODES) return;
    const int beg = row_ptr[node];
    const int end = row_ptr[node + 1];
    if (beg == end) { out[(size_t)node * D + lane] = 0.f; return; }
    const float sd = s_dst[node];

    float m = -INFINITY;
    float den = 0.f;
    float a0 = 0.f, a1 = 0.f, a2 = 0.f, a3 = 0.f;
    float a4 = 0.f, a5 = 0.f, a6 = 0.f, a7 = 0.f;

    for (int base = beg; base < end; base += 64) {
        const int n = min(64, end - base);
        const int sidx = (lane < n) ? csr_src[base + lane] : 0;
        float e = -INFINITY;
        if (lane < n) {
            e = s_src[sidx] + sd;
            e = e > 0.f ? e : 0.01f * e;          // leaky_relu
        }
        float mc = e;
        #pragma unroll
        for (int off = 32; off >= 1; off >>= 1) mc = fmaxf(mc, __shfl_xor(mc, off, 64));
        if (mc > m) {                              // online rescale
            const float scale = __expf(m - mc);
            den *= scale;
            a0 *= scale; a1 *= scale; a2 *= scale; a3 *= scale;
            a4 *= scale; a5 *= scale; a6 *= scale; a7 *= scale;
            m = mc;
        }
        const float ex = __expf(e - m);            // 0 for pad lanes
        den += ex;
        sh_ex[wv][lane] = ex;
        sh_si[wv][lane] = sidx;
        const int nn = (n + 7) & ~7;
        for (int t = 0; t < nn; t += 8) {
            const float4 w0 = *(const float4*)&sh_ex[wv][t];
            const float4 w1 = *(const float4*)&sh_ex[wv][t + 4];
            const int4   s0 = *(const int4*)  &sh_si[wv][t];
            const int4   s1 = *(const int4*)  &sh_si[wv][t + 4];
            const float z0 = z[(size_t)s0.x * D + lane];
            const float z1 = z[(size_t)s0.y * D + lane];
            const float z2 = z[(size_t)s0.z * D + lane];
            const float z3 = z[(size_t)s0.w * D + lane];
            const float z4 = z[(size_t)s1.x * D + lane];
            const float z5 = z[(size_t)s1.y * D + lane];
            const float z6 = z[(size_t)s1.z * D + lane];
            const float z7 = z[(size_t)s1.w * D + lane];
            a0 = fmaf(w0.x, z0, a0);
            a1 = fmaf(w0.y, z1, a1);
            a2 = fmaf(w0.z, z2, a2);
            a3 = fmaf(w0.w, z3, a3);
            a4 = fmaf(w1.x, z4, a4);
            a5 = fmaf(w1.y, z5, a5);
            a6 = fmaf(w1.z, z6, a6);
            a7 = fmaf(w1.w, z7, a7);
        }
    }
    #pragma unroll
    for (int off = 32; off >= 1; off >>= 1) den += __shfl_xor(den, off, 64);
    float v = (((a0 + a1) + (a2 + a3)) + ((a4 + a5) + (a6 + a7))) / den;
    if (RELU) v = fmaxf(v, 0.f);
    out[(size_t)node * D + lane] = v;
}

// ============================================================
extern "C" void kernel_launch(void* const* d_in, const int* in_sizes, int n_in,
                              void* d_out, int out_size, void* d_ws, size_t ws_size,
                              hipStream_t stream) {
    const float* x   = (const float*)d_in[0];
    const int*   src = (const int*)d_in[1];
    const int*   dst = (const int*)d_in[2];
    float* out = (float*)d_out;

    // ---- workspace carve-out (256B-aligned slots) ----
    char* wp = (char*)d_ws;
    auto alloc = [&](size_t bytes) -> void* {
        void* p = (void*)wp;
        wp += (bytes + 255) & ~(size_t)255;
        return p;
    };
    float* zbuf    = (float*)alloc((size_t)N_NODES * D * sizeof(float));
    float* s_src   = (float*)alloc((size_t)N_NODES * sizeof(float));
    float* s_dst   = (float*)alloc((size_t)N_NODES * sizeof(float));
    int*   counts  = (int*)alloc((size_t)N_NODES * sizeof(int));
    int*   row_ptr = (int*)alloc((size_t)(N_NODES + 1) * sizeof(int));
    int*   csr_src = (int*)alloc((size_t)N_EDGES * sizeof(int));
    int*   partA   = (int*)alloc(64 * sizeof(int));
    int*   partB   = (int*)alloc(64 * sizeof(int));
    int*   cursor  = (int*)alloc((size_t)N_NODES * sizeof(int));       // fallback only
    size_t base_used = (size_t)(wp - (char*)d_ws);
    int*   Acnt    = (int*)alloc((size_t)NB * NBLK * sizeof(int));
    int*   offs    = (int*)alloc((size_t)NB * NBLK * sizeof(int));
    int2*  staging = (int2*)alloc((size_t)N_EDGES * sizeof(int2));
    size_t bucket_used = (size_t)(wp - (char*)d_ws);

    const bool use_bucket = (ws_size >= bucket_used);
    (void)base_used;

    if (use_bucket) {
        // ---- bucketed CSR build: zero global atomics ----
        bucket_hist<<<NBLK, 256, 0, stream>>>(dst, Acnt);
        scan_partial_g<NB * NBLK><<<64, 256, 0, stream>>>(Acnt, partB);
        scan_offsets_g<<<1, 64, 0, stream>>>(partB, 64, nullptr);
        scan_write_g<NB * NBLK><<<64, 256, 0, stream>>>(Acnt, partB, offs);
        bucket_scatter<<<NBLK, 256, 0, stream>>>(src, dst, offs, staging);
        node_counts<<<NB, 256, 0, stream>>>(staging, offs, counts);
        scan_partial_g<N_NODES><<<49, 256, 0, stream>>>(counts, partA);
        scan_offsets_g<<<1, 64, 0, stream>>>(partA, 49, &row_ptr[N_NODES]);
        scan_write_g<N_NODES><<<49, 256, 0, stream>>>(counts, partA, row_ptr);
        bucket_to_csr<<<NB, 256, 0, stream>>>(staging, offs, row_ptr, csr_src);
    } else {
        // ---- fallback: atomic scatter path ----
        hipMemsetAsync(counts, 0, (size_t)N_NODES * sizeof(int), stream);
        hist_kernel<<<(N_EDGES + 255) / 256, 256, 0, stream>>>(dst, counts);
        scan_partial_g<N_NODES><<<49, 256, 0, stream>>>(counts, partA);
        scan_offsets_g<<<1, 64, 0, stream>>>(partA, 49, &row_ptr[N_NODES]);
        scan_write_g<N_NODES><<<49, 256, 0, stream>>>(counts, partA, row_ptr);
        copy_kernel<<<(N_NODES + 255) / 256, 256, 0, stream>>>(row_ptr, cursor, N_NODES);
        scatter_kernel<<<(N_EDGES + 255) / 256, 256, 0, stream>>>(src, dst, cursor, csr_src);
    }

    const int grid_k1  = (N_NODES + 4 * NL_ROWS - 1) / (4 * NL_ROWS);  // 1563
    const int grid_agg = (N_NODES + 3) / 4;                            // 12500

    for (int layer = 0; layer < 3; ++layer) {
        const float* W  = (const float*)d_in[3 + 4 * layer];
        const float* b  = (const float*)d_in[4 + 4 * layer];
        const float* a  = (const float*)d_in[5 + 4 * layer];
        const float* ab = (const float*)d_in[6 + 4 * layer];
        const float* hin = (layer == 0) ? x : out;   // d_out doubles as h buffer

        node_linear_gemm<<<grid_k1, 256, 0, stream>>>(hin, zbuf, W, b, a, ab, s_src, s_dst);
        if (layer < 2) {
            gat_aggregate<true ><<<grid_agg, 256, 0, stream>>>(row_ptr, csr_src, s_src, s_dst, zbuf, out);
        } else {
            gat_aggregate<false><<<grid_agg, 256, 0, stream>>>(row_ptr, csr_src, s_src, s_dst, zbuf, out);
        }
    }
}